// Round 4
// baseline (863.453 us; speedup 1.0000x reference)
//
#include <hip/hip_runtime.h>
#include <math.h>

// SingleGAP: per-point tiny MLPs + GLOBAL softmax over N (axis 0, faithful bug),
// then attention-weighted sum. out0 = [N][16] x_attn, out1 = [N][160] h2 (flat,
// [F][K] order per point == x2v raw reshape).
//
// K1: quad-per-point (4 lanes/point, lane q owns features 4q..4q+3), direct
//     global loads (no LDS staging, no main-loop barriers). Writes h2 -> out1,
//     logits -> out0 (stash; K3 overwrites), per-block online (m,s) -> partials.
// K2: reduce per-block (m,s) -> global (m,s) per k-slot.
// K3: quad-per-point weighted sum: out0 = softmax(logits) @ x2v.

__device__ __forceinline__ void comb(float& m, float& s, float om, float os) {
  float M = fmaxf(m, om);
  if (M == -INFINITY) return;  // both empty
  s = s * __expf(m - M) + os * __expf(om - M);
  m = M;
}

__global__ __launch_bounds__(256) void gap_k1(
    const float* __restrict__ xknn, const float* __restrict__ x,
    const float* __restrict__ Wf, const float* __restrict__ bf,
    const float* __restrict__ W1, const float* __restrict__ b1p,
    float* __restrict__ out, float* __restrict__ partials, int n) {
  __shared__ float s_red[4][16][2];

  const int tid = threadIdx.x;
  const int q = tid & 3;          // feature-quad 0..3 (owns f = 4q..4q+3)
  const int lane = tid & 63;
  const int wave = tid >> 6;

  // per-lane weights: Wf rows 4q..4q+3 (64 VGPRs), W1[4q..4q+3], bf[4q..4q+3]
  float wfq[4][16], w1q[4], bfq[4];
#pragma unroll
  for (int fp = 0; fp < 4; ++fp) {
    const float* wr = Wf + (size_t)(4 * q + fp) * 16;
#pragma unroll
    for (int dq = 0; dq < 4; ++dq) {
      float4 v = *(const float4*)(wr + dq * 4);
      wfq[fp][dq * 4 + 0] = v.x;
      wfq[fp][dq * 4 + 1] = v.y;
      wfq[fp][dq * 4 + 2] = v.z;
      wfq[fp][dq * 4 + 3] = v.w;
    }
    w1q[fp] = W1[4 * q + fp];
    bfq[fp] = bf[4 * q + fp];
  }
  const float b1v = b1p[0];

  // online softmax state for owned k = 4q+j (invalid slots stay empty)
  float rm[4] = {-INFINITY, -INFINITY, -INFINITY, -INFINITY};
  float rs[4] = {0.f, 0.f, 0.f, 0.f};

  float* out0 = out;                       // [n][16]  (logits now, x_attn later)
  float* out1 = out + (size_t)n * 16;      // [n][160] h2 flat ([F][K] per point)

  const long quad0 = (long)blockIdx.x * 64 + (tid >> 2);
  const long qstride = (long)gridDim.x * 64;

  for (long pt = quad0; pt < n; pt += qstride) {
    // h2[f'][k] = bf + sum_d Wf[f',d] * x2[d,k]; row is d-major flat (r = d*10+k)
    float acc[4][10];
#pragma unroll
    for (int fp = 0; fp < 4; ++fp)
#pragma unroll
      for (int k = 0; k < 10; ++k) acc[fp][k] = bfq[fp];

    const float* row = xknn + (size_t)pt * 160;
#pragma unroll
    for (int w4 = 0; w4 < 40; ++w4) {
      float4 v = *(const float4*)(row + w4 * 4);
      float ve[4] = {v.x, v.y, v.z, v.w};
#pragma unroll
      for (int e = 0; e < 4; ++e) {
        const int r = w4 * 4 + e;
        const int d = r / 10;
        const int k = r - d * 10;
#pragma unroll
        for (int fp = 0; fp < 4; ++fp)
          acc[fp][k] = fmaf(wfq[fp][d], ve[e], acc[fp][k]);
      }
    }

    // a2[k] = sum_f W1[f] h2[f][k]: own-f partial then quad butterfly
    float pa[10];
#pragma unroll
    for (int k = 0; k < 10; ++k) {
      float t = w1q[0] * acc[0][k];
      t = fmaf(w1q[1], acc[1][k], t);
      t = fmaf(w1q[2], acc[2][k], t);
      t = fmaf(w1q[3], acc[3][k], t);
      pa[k] = t;
    }
#pragma unroll
    for (int k = 0; k < 10; ++k) pa[k] += __shfl_xor(pa[k], 1);
#pragma unroll
    for (int k = 0; k < 10; ++k) pa[k] += __shfl_xor(pa[k], 2);

    // a1 from center point
    const float* xr = x + (size_t)pt * 16;
    float h1[4];
#pragma unroll
    for (int fp = 0; fp < 4; ++fp) h1[fp] = bfq[fp];
#pragma unroll
    for (int dq = 0; dq < 4; ++dq) {
      float4 v = *(const float4*)(xr + dq * 4);
      float ve[4] = {v.x, v.y, v.z, v.w};
#pragma unroll
      for (int e = 0; e < 4; ++e)
#pragma unroll
        for (int fp = 0; fp < 4; ++fp)
          h1[fp] = fmaf(wfq[fp][dq * 4 + e], ve[e], h1[fp]);
    }
    float a1p = w1q[0] * h1[0];
    a1p = fmaf(w1q[1], h1[1], a1p);
    a1p = fmaf(w1q[2], h1[2], a1p);
    a1p = fmaf(w1q[3], h1[3], a1p);
    a1p += __shfl_xor(a1p, 1);
    a1p += __shfl_xor(a1p, 2);

    const float addc = a1p + 2.0f * b1v;  // logit = (a2+b1) + (a1+b1)

    // lane q takes logits k=4q..4q+3 (cndmask chain; no runtime array index)
    float lj[4];
#pragma unroll
    for (int j = 0; j < 4; ++j) {
      const int k = 4 * q + j;  // runtime q
      float v = 0.f;
#pragma unroll
      for (int kk = 0; kk < 10; ++kk) v = (kk == k) ? (pa[kk] + addc) : v;
      lj[j] = v;
      if (k < 10) comb(rm[j], rs[j], v, 1.0f);
    }
    // logits (+ don't-care pad) -> out0, fully coalesced 64B/point
    *(float4*)(out0 + (size_t)pt * 16 + 4 * q) =
        make_float4(lj[0], lj[1], lj[2], lj[3]);

    // h2 -> out1 in FLAT [F][K] order (raw-reshape identity): lane q's region
    // is offsets [40q, 40q+40) -- contiguous 160B per lane, coalesced per wave.
    float vals[40];
#pragma unroll
    for (int fp = 0; fp < 4; ++fp)
#pragma unroll
      for (int k = 0; k < 10; ++k) vals[fp * 10 + k] = acc[fp][k];
    float* o1 = out1 + (size_t)pt * 160 + 40 * q;
#pragma unroll
    for (int i = 0; i < 10; ++i)
      *(float4*)(o1 + 4 * i) = make_float4(vals[4 * i + 0], vals[4 * i + 1],
                                           vals[4 * i + 2], vals[4 * i + 3]);
  }

  // reduce (m,s) across the wave's 16 quads (lanes differing in bits 2..5)
#pragma unroll
  for (int mask = 4; mask < 64; mask <<= 1) {
#pragma unroll
    for (int j = 0; j < 4; ++j) {
      float om = __shfl_xor(rm[j], mask);
      float os = __shfl_xor(rs[j], mask);
      comb(rm[j], rs[j], om, os);
    }
  }
  if (lane < 4) {  // lane == q-class representative; slot index = k = 4*lane+j
#pragma unroll
    for (int j = 0; j < 4; ++j) {
      s_red[wave][lane * 4 + j][0] = rm[j];
      s_red[wave][lane * 4 + j][1] = rs[j];
    }
  }
  __syncthreads();
  if (tid < 10) {
    float m = s_red[0][tid][0], s = s_red[0][tid][1];
    comb(m, s, s_red[1][tid][0], s_red[1][tid][1]);
    comb(m, s, s_red[2][tid][0], s_red[2][tid][1]);
    comb(m, s, s_red[3][tid][0], s_red[3][tid][1]);
    partials[(size_t)blockIdx.x * 20 + tid * 2 + 0] = m;
    partials[(size_t)blockIdx.x * 20 + tid * 2 + 1] = s;
  }
}

__global__ __launch_bounds__(256) void gap_k2(const float* __restrict__ part,
                                              int nb, float* __restrict__ fin) {
  const int k = blockIdx.x;   // one block per k-slot
  const int tid = threadIdx.x;
  float m = -INFINITY, s = 0.f;
  for (int i = tid; i < nb; i += 256)
    comb(m, s, part[(size_t)i * 20 + k * 2], part[(size_t)i * 20 + k * 2 + 1]);
#pragma unroll
  for (int mask = 1; mask < 64; mask <<= 1) {
    float om = __shfl_xor(m, mask, 64);
    float os = __shfl_xor(s, mask, 64);
    comb(m, s, om, os);
  }
  __shared__ float sm[4][2];
  const int wave = tid >> 6, lane = tid & 63;
  if (lane == 0) { sm[wave][0] = m; sm[wave][1] = s; }
  __syncthreads();
  if (tid == 0) {
    for (int w = 1; w < 4; ++w) comb(m, s, sm[w][0], sm[w][1]);
    fin[k * 2 + 0] = m;
    fin[k * 2 + 1] = s;
  }
}

// K3: 4 lanes per point; lane (p,q) accumulates features f = 4q..4q+3.
// Reads out1 flat at offset k*16+f == x2v[k][f] (raw-reshape identity).
__global__ __launch_bounds__(256) void gap_k3(const float* __restrict__ fin,
                                              float* __restrict__ out, int n) {
  __shared__ float s_fin[20];
  if (threadIdx.x < 20) s_fin[threadIdx.x] = fin[threadIdx.x];
  __syncthreads();
  float mk[10], rsk[10];
#pragma unroll
  for (int k = 0; k < 10; ++k) {
    mk[k] = s_fin[2 * k];
    rsk[k] = 1.0f / s_fin[2 * k + 1];
  }
  float* out0 = out;
  const float* out1 = out + (size_t)n * 16;
  const int q = threadIdx.x & 3;
  const int pl = threadIdx.x >> 2;           // 64 points per block pass
  for (long i = (long)blockIdx.x * 64 + pl; i < n; i += (long)gridDim.x * 64) {
    float* lrow = out0 + i * 16;
    // all 4 lanes of the quad read the same 64B logit line (L1 broadcast)
    float4 la = *(const float4*)(lrow);
    float4 lb = *(const float4*)(lrow + 4);
    float2 lc = *(const float2*)(lrow + 8);
    float l[10] = {la.x, la.y, la.z, la.w, lb.x, lb.y, lb.z, lb.w, lc.x, lc.y};
    float w[10];
#pragma unroll
    for (int k = 0; k < 10; ++k) w[k] = __expf(l[k] - mk[k]) * rsk[k];
    const float* vrow = out1 + i * 160 + q * 4;
    float4 acc = make_float4(0.f, 0.f, 0.f, 0.f);
#pragma unroll
    for (int k = 0; k < 10; ++k) {
      float4 v = *(const float4*)(vrow + k * 16);
      float wk = w[k];
      acc.x = fmaf(wk, v.x, acc.x);
      acc.y = fmaf(wk, v.y, acc.y);
      acc.z = fmaf(wk, v.z, acc.z);
      acc.w = fmaf(wk, v.w, acc.w);
    }
    // store after all reads (wave-lockstep => no RAW hazard on the logit line)
    *(float4*)(lrow + q * 4) = acc;
  }
}

extern "C" void kernel_launch(void* const* d_in, const int* in_sizes, int n_in,
                              void* d_out, int out_size, void* d_ws, size_t ws_size,
                              hipStream_t stream) {
  const float* xknn = (const float*)d_in[0];
  const float* x    = (const float*)d_in[1];
  const float* Wf   = (const float*)d_in[2];
  const float* bf   = (const float*)d_in[3];
  const float* W1   = (const float*)d_in[4];
  const float* b1   = (const float*)d_in[5];
  float* out = (float*)d_out;
  const int n = in_sizes[1] / 16;  // x is [N][16]

  const int G1 = 2048;
  float* partials = (float*)d_ws;                 // [G1][10][2]
  float* finals = partials + (size_t)G1 * 20;     // [10][2]

  gap_k1<<<G1, 256, 0, stream>>>(xknn, x, Wf, bf, W1, b1, out, partials, n);
  gap_k2<<<10, 256, 0, stream>>>(partials, G1, finals);
  gap_k3<<<2048, 256, 0, stream>>>(finals, out, n);
}

// Round 5
// 561.974 us; speedup vs baseline: 1.5365x; 1.5365x over previous
//
#include <hip/hip_runtime.h>
#include <math.h>

// SingleGAP: per-point tiny MLPs + GLOBAL softmax over N (axis 0, faithful bug),
// then attention-weighted sum. out0 = [N][16] x_attn, out1 = [N][160] h2 (flat,
// [F][K] order per point == x2v raw reshape).
//
// K1: quad-per-point. Lane q of a quad LOADS only its quarter of the xknn row
//     (elements [40q,40q+40), 10 float4) and OWNS features f=4q..4q+3. The
//     160-element sweep gets each value via a quad_perm broadcast DPP from the
//     quarter-owner lane (pure VALU, no LDS, no barriers, no dup loads).
// K2: reduce per-block (m,s) -> global (m,s) per k-slot.
// K3: quad-per-point weighted sum: out0 = softmax(logits) @ x2v.

__device__ __forceinline__ void comb(float& m, float& s, float om, float os) {
  float M = fmaxf(m, om);
  if (M == -INFINITY) return;  // both empty
  s = s * __expf(m - M) + os * __expf(om - M);
  m = M;
}

// Broadcast the value of quad-lane SRC to all 4 lanes of each quad.
// quad_perm ctrl [s,s,s,s] = s*0x55.
template <int CTRL>
__device__ __forceinline__ float qb(float v) {
  return __int_as_float(__builtin_amdgcn_update_dpp(
      0, __float_as_int(v), CTRL, 0xf, 0xf, true));
}

__global__ __launch_bounds__(256) void gap_k1(
    const float* __restrict__ xknn, const float* __restrict__ x,
    const float* __restrict__ Wf, const float* __restrict__ bf,
    const float* __restrict__ W1, const float* __restrict__ b1p,
    float* __restrict__ out, float* __restrict__ partials, int n) {
  __shared__ float s_red[4][16][2];

  const int tid = threadIdx.x;
  const int q = tid & 3;          // quad lane: owns f = 4q..4q+3 AND quarter q
  const int lane = tid & 63;
  const int wave = tid >> 6;

  // per-lane weights: Wf rows 4q..4q+3, W1[4q..4q+3], bf[4q..4q+3]
  float wfq[4][16], w1q[4], bfq[4];
#pragma unroll
  for (int fp = 0; fp < 4; ++fp) {
    const float* wr = Wf + (size_t)(4 * q + fp) * 16;
#pragma unroll
    for (int dq = 0; dq < 4; ++dq) {
      float4 v = *(const float4*)(wr + dq * 4);
      wfq[fp][dq * 4 + 0] = v.x;
      wfq[fp][dq * 4 + 1] = v.y;
      wfq[fp][dq * 4 + 2] = v.z;
      wfq[fp][dq * 4 + 3] = v.w;
    }
    w1q[fp] = W1[4 * q + fp];
    bfq[fp] = bf[4 * q + fp];
  }
  const float b1v = b1p[0];

  // online softmax state for owned k = 4q+j (invalid slots stay empty)
  float rm[4] = {-INFINITY, -INFINITY, -INFINITY, -INFINITY};
  float rs[4] = {0.f, 0.f, 0.f, 0.f};

  float* out0 = out;                       // [n][16]  (logits now, x_attn later)
  float* out1 = out + (size_t)n * 16;      // [n][160] h2 flat ([F][K] per point)

  const long quad0 = (long)blockIdx.x * 64 + (tid >> 2);
  const long qstride = (long)gridDim.x * 64;

  for (long pt = quad0; pt < n; pt += qstride) {
    // load ONLY this lane's quarter: flat elements [40q, 40q+40)
    const float* rowq = xknn + (size_t)pt * 160 + 40 * q;
    float4 own[10];
#pragma unroll
    for (int j = 0; j < 10; ++j) own[j] = *(const float4*)(rowq + 4 * j);

    // h2[f'][k] = bf + sum_d Wf[f',d] * x2[d,k]; flat r = d*10+k, quarter src = r/40
    float acc[4][10];
#pragma unroll
    for (int fp = 0; fp < 4; ++fp)
#pragma unroll
      for (int k = 0; k < 10; ++k) acc[fp][k] = bfq[fp];

#pragma unroll
    for (int src = 0; src < 4; ++src) {
#pragma unroll
      for (int rr = 0; rr < 40; ++rr) {
        const int r = src * 40 + rr;
        const int j = rr / 4, e = rr % 4;
        const int d = r / 10, k = r - d * 10;
        const float xe = (e == 0) ? own[j].x
                       : (e == 1) ? own[j].y
                       : (e == 2) ? own[j].z
                                  : own[j].w;
        const float xv = (src == 0)   ? qb<0x00>(xe)
                         : (src == 1) ? qb<0x55>(xe)
                         : (src == 2) ? qb<0xAA>(xe)
                                      : qb<0xFF>(xe);
        acc[0][k] = fmaf(wfq[0][d], xv, acc[0][k]);
        acc[1][k] = fmaf(wfq[1][d], xv, acc[1][k]);
        acc[2][k] = fmaf(wfq[2][d], xv, acc[2][k]);
        acc[3][k] = fmaf(wfq[3][d], xv, acc[3][k]);
      }
    }

    // a2[k] = sum_f W1[f] h2[f][k]: own-f partial then quad butterfly
    float pa[10];
#pragma unroll
    for (int k = 0; k < 10; ++k) {
      float t = w1q[0] * acc[0][k];
      t = fmaf(w1q[1], acc[1][k], t);
      t = fmaf(w1q[2], acc[2][k], t);
      t = fmaf(w1q[3], acc[3][k], t);
      pa[k] = t;
    }
#pragma unroll
    for (int k = 0; k < 10; ++k) pa[k] += __shfl_xor(pa[k], 1);
#pragma unroll
    for (int k = 0; k < 10; ++k) pa[k] += __shfl_xor(pa[k], 2);

    // a1 from center point (quad lanes share the 64B line -> broadcast, no dup)
    const float* xr = x + (size_t)pt * 16;
    float h1[4];
#pragma unroll
    for (int fp = 0; fp < 4; ++fp) h1[fp] = bfq[fp];
#pragma unroll
    for (int dq = 0; dq < 4; ++dq) {
      float4 v = *(const float4*)(xr + dq * 4);
      float ve[4] = {v.x, v.y, v.z, v.w};
#pragma unroll
      for (int e = 0; e < 4; ++e)
#pragma unroll
        for (int fp = 0; fp < 4; ++fp)
          h1[fp] = fmaf(wfq[fp][dq * 4 + e], ve[e], h1[fp]);
    }
    float a1p = w1q[0] * h1[0];
    a1p = fmaf(w1q[1], h1[1], a1p);
    a1p = fmaf(w1q[2], h1[2], a1p);
    a1p = fmaf(w1q[3], h1[3], a1p);
    a1p += __shfl_xor(a1p, 1);
    a1p += __shfl_xor(a1p, 2);

    const float addc = a1p + 2.0f * b1v;  // logit = (a2+b1) + (a1+b1)

    // lane q takes logits k=4q..4q+3 (cndmask chain; no runtime array index)
    float lj[4];
#pragma unroll
    for (int j = 0; j < 4; ++j) {
      const int k = 4 * q + j;  // runtime q
      float v = 0.f;
#pragma unroll
      for (int kk = 0; kk < 10; ++kk) v = (kk == k) ? (pa[kk] + addc) : v;
      lj[j] = v;
      if (k < 10) comb(rm[j], rs[j], v, 1.0f);
    }
    // logits (+ don't-care pad) -> out0, fully coalesced 64B/point
    *(float4*)(out0 + (size_t)pt * 16 + 4 * q) =
        make_float4(lj[0], lj[1], lj[2], lj[3]);

    // h2 -> out1 in FLAT [F][K] order: lane q's region is exactly its quarter
    // [40q, 40q+40) -- contiguous 160B per lane (same pattern as the loads).
    float vals[40];
#pragma unroll
    for (int fp = 0; fp < 4; ++fp)
#pragma unroll
      for (int k = 0; k < 10; ++k) vals[fp * 10 + k] = acc[fp][k];
    float* o1 = out1 + (size_t)pt * 160 + 40 * q;
#pragma unroll
    for (int i = 0; i < 10; ++i)
      *(float4*)(o1 + 4 * i) = make_float4(vals[4 * i + 0], vals[4 * i + 1],
                                           vals[4 * i + 2], vals[4 * i + 3]);
  }

  // reduce (m,s) across the wave's 16 quads (lanes differing in bits 2..5)
#pragma unroll
  for (int mask = 4; mask < 64; mask <<= 1) {
#pragma unroll
    for (int j = 0; j < 4; ++j) {
      float om = __shfl_xor(rm[j], mask);
      float os = __shfl_xor(rs[j], mask);
      comb(rm[j], rs[j], om, os);
    }
  }
  if (lane < 4) {  // lane == q-class representative; slot index = k = 4*lane+j
#pragma unroll
    for (int j = 0; j < 4; ++j) {
      s_red[wave][lane * 4 + j][0] = rm[j];
      s_red[wave][lane * 4 + j][1] = rs[j];
    }
  }
  __syncthreads();
  if (tid < 10) {
    float m = s_red[0][tid][0], s = s_red[0][tid][1];
    comb(m, s, s_red[1][tid][0], s_red[1][tid][1]);
    comb(m, s, s_red[2][tid][0], s_red[2][tid][1]);
    comb(m, s, s_red[3][tid][0], s_red[3][tid][1]);
    partials[(size_t)blockIdx.x * 20 + tid * 2 + 0] = m;
    partials[(size_t)blockIdx.x * 20 + tid * 2 + 1] = s;
  }
}

__global__ __launch_bounds__(256) void gap_k2(const float* __restrict__ part,
                                              int nb, float* __restrict__ fin) {
  const int k = blockIdx.x;   // one block per k-slot
  const int tid = threadIdx.x;
  float m = -INFINITY, s = 0.f;
  for (int i = tid; i < nb; i += 256)
    comb(m, s, part[(size_t)i * 20 + k * 2], part[(size_t)i * 20 + k * 2 + 1]);
#pragma unroll
  for (int mask = 1; mask < 64; mask <<= 1) {
    float om = __shfl_xor(m, mask, 64);
    float os = __shfl_xor(s, mask, 64);
    comb(m, s, om, os);
  }
  __shared__ float sm[4][2];
  const int wave = tid >> 6, lane = tid & 63;
  if (lane == 0) { sm[wave][0] = m; sm[wave][1] = s; }
  __syncthreads();
  if (tid == 0) {
    for (int w = 1; w < 4; ++w) comb(m, s, sm[w][0], sm[w][1]);
    fin[k * 2 + 0] = m;
    fin[k * 2 + 1] = s;
  }
}

// K3: 4 lanes per point; lane (p,q) accumulates features f = 4q..4q+3.
// Reads out1 flat at offset k*16+f == x2v[k][f] (raw-reshape identity).
__global__ __launch_bounds__(256) void gap_k3(const float* __restrict__ fin,
                                              float* __restrict__ out, int n) {
  __shared__ float s_fin[20];
  if (threadIdx.x < 20) s_fin[threadIdx.x] = fin[threadIdx.x];
  __syncthreads();
  float mk[10], rsk[10];
#pragma unroll
  for (int k = 0; k < 10; ++k) {
    mk[k] = s_fin[2 * k];
    rsk[k] = 1.0f / s_fin[2 * k + 1];
  }
  float* out0 = out;
  const float* out1 = out + (size_t)n * 16;
  const int q = threadIdx.x & 3;
  const int pl = threadIdx.x >> 2;           // 64 points per block pass
  for (long i = (long)blockIdx.x * 64 + pl; i < n; i += (long)gridDim.x * 64) {
    float* lrow = out0 + i * 16;
    // all 4 lanes of the quad read the same 64B logit line (L1 broadcast)
    float4 la = *(const float4*)(lrow);
    float4 lb = *(const float4*)(lrow + 4);
    float2 lc = *(const float2*)(lrow + 8);
    float l[10] = {la.x, la.y, la.z, la.w, lb.x, lb.y, lb.z, lb.w, lc.x, lc.y};
    float w[10];
#pragma unroll
    for (int k = 0; k < 10; ++k) w[k] = __expf(l[k] - mk[k]) * rsk[k];
    const float* vrow = out1 + i * 160 + q * 4;
    float4 acc = make_float4(0.f, 0.f, 0.f, 0.f);
#pragma unroll
    for (int k = 0; k < 10; ++k) {
      float4 v = *(const float4*)(vrow + k * 16);
      float wk = w[k];
      acc.x = fmaf(wk, v.x, acc.x);
      acc.y = fmaf(wk, v.y, acc.y);
      acc.z = fmaf(wk, v.z, acc.z);
      acc.w = fmaf(wk, v.w, acc.w);
    }
    // store after all reads (wave-lockstep => no RAW hazard on the logit line)
    *(float4*)(lrow + q * 4) = acc;
  }
}

extern "C" void kernel_launch(void* const* d_in, const int* in_sizes, int n_in,
                              void* d_out, int out_size, void* d_ws, size_t ws_size,
                              hipStream_t stream) {
  const float* xknn = (const float*)d_in[0];
  const float* x    = (const float*)d_in[1];
  const float* Wf   = (const float*)d_in[2];
  const float* bf   = (const float*)d_in[3];
  const float* W1   = (const float*)d_in[4];
  const float* b1   = (const float*)d_in[5];
  float* out = (float*)d_out;
  const int n = in_sizes[1] / 16;  // x is [N][16]

  const int G1 = 2048;
  float* partials = (float*)d_ws;                 // [G1][10][2]
  float* finals = partials + (size_t)G1 * 20;     // [10][2]

  gap_k1<<<G1, 256, 0, stream>>>(xknn, x, Wf, bf, W1, b1, out, partials, n);
  gap_k2<<<10, 256, 0, stream>>>(partials, G1, finals);
  gap_k3<<<2048, 256, 0, stream>>>(finals, out, n);
}